// Round 19
// baseline (107.725 us; speedup 1.0000x reference)
//
#include <hip/hip_runtime.h>
#include <hip/hip_bf16.h>

typedef __attribute__((ext_vector_type(8))) short bf16x8;
typedef __attribute__((ext_vector_type(4))) float f32x4;
typedef __attribute__((ext_vector_type(16))) float f32x16;
typedef unsigned int u32;
typedef unsigned short u16;

#define XI_ROW 4128   // N + 2L
#define KP     8448   // M * W, k' = j*256 + m
#define NB     1024
#define NN     4096
#define DDIM   512

__device__ __forceinline__ u16 f2bf(float f) {
  union { float f; unsigned u; } c; c.f = f;
  return (u16)((c.u + 0x7FFFu + ((c.u >> 16) & 1u)) >> 16);
}
__device__ __forceinline__ float bf2f(u16 h) {
  union { u32 u; float f; } c; c.u = ((u32)h) << 16; return c.f;
}
__device__ __forceinline__ u32 pk2bf(float a, float b) {
  return (u32)f2bf(a) | ((u32)f2bf(b) << 16);
}
__device__ __forceinline__ void gld16(const u16* g, u16* l) {
  __builtin_amdgcn_global_load_lds(
      (const __attribute__((address_space(1))) u32*)(const void*)g,
      (__attribute__((address_space(3))) u32*)(void*)l, 16, 0, 0);
}

#define BAR() __builtin_amdgcn_s_barrier()
#define LGKM0() asm volatile("s_waitcnt lgkmcnt(0)" ::: "memory")
#define LGKM8() asm volatile("s_waitcnt lgkmcnt(8)" ::: "memory")
#define WAITVM(N) asm volatile("s_waitcnt vmcnt(" #N ")" ::: "memory")
#define SCHED0() __builtin_amdgcn_sched_barrier(0)

// ---------------------------------------------------------------------------
// Fused prep: convW [0,4224), convU [4224,4736), transpose xi [4736,5768).
// ---------------------------------------------------------------------------
__global__ __launch_bounds__(256) void k_prep(
    const float* __restrict__ w, const float* __restrict__ u,
    const float* __restrict__ xi, u16* __restrict__ Wbf,
    u16* __restrict__ Ubf, u16* __restrict__ xiT) {
  __shared__ u16 tile[32][33];
  const int bx = blockIdx.x, t = threadIdx.x;
  if (bx < 4224) {                       // weight f32 -> bf16, k'=j*256+m rows
    int kp = bx * 2 + (t >> 7), tl = t & 127;
    int m = kp & 255, j = kp >> 8;
    float4 v = ((const float4*)(w + (size_t)(m * 33 + j) * DDIM))[tl];
    ((uint2*)(Wbf + (size_t)kp * DDIM))[tl] =
        make_uint2(pk2bf(v.x, v.y), pk2bf(v.z, v.w));
  } else if (bx < 4736) {                // u f32 -> bf16
    int b = (bx - 4224) * 2 + (t >> 7), tl = t & 127;
    float4 v = ((const float4*)(u + (size_t)b * DDIM))[tl];
    ((uint2*)(Ubf + (size_t)b * DDIM))[tl] =
        make_uint2(pk2bf(v.x, v.y), pk2bf(v.z, v.w));
  } else {                               // xi (256x4128) -> xiT (4128x256) bf16
    int bx2 = bx - 4736;
    int cblk = bx2 % 129, mblk = bx2 / 129;
    int c0 = cblk * 32, m0 = mblk * 32;
    int tx = t & 31, ty = t >> 5;
#pragma unroll
    for (int i = 0; i < 4; ++i)
      tile[ty + i * 8][tx] = f2bf(xi[(size_t)(m0 + ty + i * 8) * XI_ROW + c0 + tx]);
    __syncthreads();
#pragma unroll
    for (int i = 0; i < 4; ++i)
      xiT[(size_t)(c0 + ty + i * 8) * 256 + m0 + tx] = tile[tx][ty + i * 8];
  }
}

// ---------------------------------------------------------------------------
// 2-phase pipelined core for GEMM1 (proven): 128x128 tile, 4 waves, BK=64.
// ---------------------------------------------------------------------------
template<int KSTEPS, int AS, int BS>
__device__ __forceinline__ void gemm_pipeline(
    const u16* __restrict__ aSrc, const u16* __restrict__ bSrc,
    u16* As0, u16* As1, u16* Bl0, u16* Bl1,
    int wid, int wr, int wc, int rl, int kg, int rl7,
    f32x4 (&acc)[4][4]) {

  auto stage = [&](u16* Ab, u16* Bb, int kk) {
#pragma unroll
    for (int i = 0; i < 4; ++i)
      gld16(aSrc + (size_t)i * 8 * AS + kk, &Ab[(wid * 4 + i) * 512]);
#pragma unroll
    for (int i = 0; i < 4; ++i)
      gld16(bSrc + (size_t)i * 8 * BS + kk, &Bb[(wid * 4 + i) * 512]);
  };
  auto compute = [&](const u16* Ab, const u16* Bb) {
#pragma unroll
    for (int kh = 0; kh < 2; ++kh) {
      bf16x8 af[4], bfv[4];
#pragma unroll
      for (int fm = 0; fm < 4; ++fm)
        af[fm] = *(const bf16x8*)&Ab[(wr * 64 + fm * 16 + rl) * 64 +
                                     (((kh * 4 + kg) ^ rl7) * 8)];
#pragma unroll
      for (int fn = 0; fn < 4; ++fn)
        bfv[fn] = *(const bf16x8*)&Bb[(wc * 64 + fn * 16 + rl) * 64 +
                                      (((kh * 4 + kg) ^ rl7) * 8)];
      __builtin_amdgcn_s_setprio(1);
#pragma unroll
      for (int fm = 0; fm < 4; ++fm)
#pragma unroll
        for (int fn = 0; fn < 4; ++fn)
          acc[fm][fn] = __builtin_amdgcn_mfma_f32_16x16x32_bf16(
              af[fm], bfv[fn], acc[fm][fn], 0, 0, 0);
      __builtin_amdgcn_s_setprio(0);
    }
  };

  stage(As0, Bl0, 0);
  WAITVM(0);
  BAR();
#pragma unroll 1
  for (int ts = 0; ts < KSTEPS - 2; ts += 2) {
    stage(As1, Bl1, (ts + 1) * 64);
    WAITVM(8);
    BAR();
    compute(As0, Bl0);
    BAR();
    stage(As0, Bl0, (ts + 2) * 64);
    WAITVM(8);
    BAR();
    compute(As1, Bl1);
    BAR();
  }
  stage(As1, Bl1, (KSTEPS - 1) * 64);
  WAITVM(8);
  BAR();
  compute(As0, Bl0);
  BAR();
  WAITVM(0);
  BAR();
  compute(As1, Bl1);
}

// ---------------------------------------------------------------------------
// GEMM1: Gt[b][k'] = sigmoid(Wbf[k',:]·Ubf[b,:] + bias[k'])
// Epilogue: LDS transpose (Lt[128][136]) -> coalesced 16B row stores.
// ---------------------------------------------------------------------------
__global__ __launch_bounds__(256) void k_gemm1(
    const u16* __restrict__ Wbf, const u16* __restrict__ Ubf,
    const float* __restrict__ Bsrc, u16* __restrict__ Gt) {
  __shared__ u16 lds1[32768];            // 64 KB: staging, then Lt
  u16* As0 = lds1;
  u16* As1 = lds1 + 8192;
  u16* Bl0 = lds1 + 16384;
  u16* Bl1 = lds1 + 24576;
  const int r0 = blockIdx.x * 128;
  const int b0 = blockIdx.y * 128;
  const int t = threadIdx.x, lane = t & 63, wid = t >> 6;
  const int wr = wid >> 1, wc = wid & 1;
  const int rl = lane & 15, kg = lane >> 4, rl7 = rl & 7;
  const int lr = lane >> 3, lc = (lane & 7) ^ (lr & 7);
  const u16* aSrc = Wbf + (size_t)(r0 + wid * 32 + lr) * DDIM + lc * 8;
  const u16* bSrc = Ubf + (size_t)(b0 + wid * 32 + lr) * DDIM + lc * 8;

  f32x4 acc[4][4] = {};
  gemm_pipeline<8, DDIM, DDIM>(aSrc, bSrc, As0, As1, Bl0, Bl1,
                               wid, wr, wc, rl, kg, rl7, acc);

  __syncthreads();                       // all waves done reading staging LDS
  u16* Lt = lds1;                        // [128][136] bf16
#pragma unroll
  for (int fm = 0; fm < 4; ++fm) {
    int kloc = wr * 64 + fm * 16 + kg * 4;
    int kbase = r0 + kloc;
    float b4[4];
#pragma unroll
    for (int r = 0; r < 4; ++r) {
      int kk = kbase + r;
      b4[r] = Bsrc[(kk & 255) * 33 + (kk >> 8)];
    }
#pragma unroll
    for (int fn = 0; fn < 4; ++fn) {
      int bloc = wc * 64 + fn * 16 + rl;
      u16 o[4];
#pragma unroll
      for (int r = 0; r < 4; ++r) {
        float x = acc[fm][fn][r] + b4[r];
        o[r] = f2bf(1.0f / (1.0f + __expf(-x)));
      }
      *(uint2*)&Lt[bloc * 136 + kloc] =
          make_uint2((u32)o[0] | ((u32)o[1] << 16),
                     (u32)o[2] | ((u32)o[3] << 16));
    }
  }
  __syncthreads();
  const int bl = t >> 4, j = t & 15;
#pragma unroll
  for (int p = 0; p < 8; ++p) {
    int bloc = p * 16 + bl;
    uint4 v = *(const uint4*)&Lt[bloc * 136 + j * 8];
    *(uint4*)(Gt + (size_t)(b0 + bloc) * KP + r0 + j * 8) = v;
  }
}

// ---------------------------------------------------------------------------
// GEMM2: 256x256 tile, 8 waves (2Mx4N, wave-tile 128x64), BK=64, uniform
// K-split 4 (33 steps). Same single-barrier 8-phase staging map as r18
// (proven), inner compute switched to v_mfma_f32_32x32x16_bf16 (m119: +14.7%
// µbench vs 16x16x32; identical LDS traffic & register budget).
// A frag: lane l = row (l&31) of 32-row block, k-chunk (l>>5); swizzle XOR
// term = (ks*2+(l>>5)) ^ (l&7) (row&7 == lane&7 for 32-aligned blocks) —
// conflict-free per 8-lane group. C/D: col=lane&31,
// row=(r&3)+8*(r>>2)+4*(lane>>5) [m74/m101 verified].
// ---------------------------------------------------------------------------
__global__ __launch_bounds__(512, 2) void k_gemm2(
    const u16* __restrict__ xiT, const u16* __restrict__ Gt,
    float* __restrict__ Out, u16* __restrict__ Part, int allbf) {
  __shared__ u16 lds[65536];
  const int lid = blockIdx.x;
  const int b0 = (lid & 3) * 256;          // 4 b-tiles
  const int ks4 = (lid >> 2) & 3;          // 4 K-splits, 2112 each
  const int n0 = (lid >> 4) * 256;         // 16 n-tiles
  const int kOff = ks4 * 2112;             // 33 BK-steps, uniform

  const int t = threadIdx.x, lane = t & 63, wid = t >> 6;
  const int wr = wid >> 2, wc = wid & 3;   // 2(M) x 4(N) waves
  const int l31 = lane & 31, ch5 = lane >> 5, l7 = lane & 7;
  const int sr = lane >> 3;                // stage: row within 8-row group
  const int sc = (lane & 7) ^ sr;          // stage: swizzled col-chunk

  const u16* aS = xiT + (size_t)(n0 + wid * 16 + sr) * 256 + kOff + sc * 8;
  const u16* bS = Gt  + (size_t)(b0 + wid * 16 + sr) * KP  + kOff + sc * 8;

  f32x16 acc[4][2] = {};                   // [m-block 32][n-block 32]
  bf16x8 af[8], bv0[4], bv1[4];

  auto stA = [&](int tile, int half, int buf) {
    u16* d = lds + (buf * 4 + half) * 8192 + wid * 1024;
    const u16* s = aS + (size_t)half * 32768 + (size_t)tile * 64;
    gld16(s, d);
    gld16(s + 2048, d + 512);
  };
  auto stB = [&](int tile, int half, int buf) {
    u16* d = lds + (buf * 4 + 2 + half) * 8192 + wid * 1024;
    const u16* s = bS + (size_t)half * 128 * KP + (size_t)tile * 64;
    gld16(s, d);
    gld16(s + (size_t)8 * KP, d + 512);
  };
  // A frags for half-tile sm: row-blocks {sm*2, sm*2+1}, 4 k-slices each
  auto rdA32 = [&](int buf, int sm) {
    const u16* p = lds + (buf * 4 + wr) * 8192;
#pragma unroll
    for (int mb = 0; mb < 2; ++mb)
#pragma unroll
      for (int ks = 0; ks < 4; ++ks)
        af[mb * 4 + ks] = *(const bf16x8*)
            &p[((sm * 2 + mb) * 32 + l31) * 64 +
               (((ks * 2 + ch5) ^ l7) * 8)];
  };
  // B frags for n-block sn (32 cols), 4 k-slices
  auto rdB32 = [&](int buf, int sn, bf16x8 (&bv)[4]) {
    const int bcol = wc * 64 + sn * 32;
    const u16* p = lds + (buf * 4 + 2 + (bcol >> 7)) * 8192;
    const int rb = bcol & 127;
#pragma unroll
    for (int ks = 0; ks < 4; ++ks)
      bv[ks] = *(const bf16x8*)
          &p[(rb + l31) * 64 + (((ks * 2 + ch5) ^ l7) * 8)];
  };
  auto mm = [&](int sm, int sn, bf16x8 (&bv)[4]) {
    __builtin_amdgcn_s_setprio(1);
#pragma unroll
    for (int mb = 0; mb < 2; ++mb)
#pragma unroll
      for (int ks = 0; ks < 4; ++ks)
        acc[sm * 2 + mb][sn] = __builtin_amdgcn_mfma_f32_32x32x16_bf16(
            af[mb * 4 + ks], bv[ks], acc[sm * 2 + mb][sn], 0, 0, 0);
    __builtin_amdgcn_s_setprio(0);
  };

  // s2: T+2 valid (stages ph4-7); s3: T+3 valid (stage ph8)
  auto runIter = [&](int T, bool s2, bool s3) {
    // ph1: (0,0) tile T (buf0) — 12 ds_reads
    rdA32(0, 0); rdB32(0, 0, bv0); stB(T + 1, 1, 1);
    LGKM8(); SCHED0(); BAR(); LGKM0(); SCHED0(); mm(0, 0, bv0);
    // ph2: (0,1)
    rdB32(0, 1, bv1); stA(T + 1, 0, 1);
    SCHED0(); BAR(); LGKM0(); SCHED0(); mm(0, 1, bv1);
    // ph3: (1,0)
    rdA32(0, 1); stA(T + 1, 1, 1);
    SCHED0(); BAR(); LGKM0(); SCHED0(); mm(1, 0, bv0);
    // ph4: (1,1) [no ds_reads]
    if (s2) { stB(T + 2, 0, 0); WAITVM(2); } else { WAITVM(0); }
    SCHED0(); BAR(); SCHED0(); mm(1, 1, bv1);
    // ph5: (0,0) tile T+1 (buf1) — 12 ds_reads
    rdA32(1, 0); rdB32(1, 0, bv0); if (s2) stB(T + 2, 1, 0);
    LGKM8(); SCHED0(); BAR(); LGKM0(); SCHED0(); mm(0, 0, bv0);
    // ph6: (0,1)
    rdB32(1, 1, bv1); if (s2) stA(T + 2, 0, 0);
    SCHED0(); BAR(); LGKM0(); SCHED0(); mm(0, 1, bv1);
    // ph7: (1,0)
    rdA32(1, 1); if (s2) stA(T + 2, 1, 0);
    SCHED0(); BAR(); LGKM0(); SCHED0(); mm(1, 0, bv0);
    // ph8: (1,1) — buf0 drained for next reads
    if (s3) { stB(T + 3, 0, 1); WAITVM(2); }
    else if (s2) { WAITVM(0); }
    SCHED0(); BAR(); SCHED0(); mm(1, 1, bv1);
  };

  // prologue: T0 complete (buf0, 8 loads) + T1's B-h0 (2 loads).
  stA(0, 0, 0); stA(0, 1, 0); stB(0, 0, 0); stB(0, 1, 0);
  stB(1, 0, 1);
  WAITVM(2);
  BAR();

  // nt = 33: 15 full pair-iters, 1 pair-iter w/o s3, then single-tile tail.
#pragma unroll 1
  for (int it = 0; it < 15; ++it) runIter(it * 2, true, true);
  runIter(30, true, false);

  // tail: tile 32 in buf0 — fully landed (prev ph8 did WAITVM(0)+BAR).
  rdA32(0, 0); rdB32(0, 0, bv0); rdB32(0, 1, bv1);
  mm(0, 0, bv0); mm(0, 1, bv1);
  rdA32(0, 1);
  mm(1, 0, bv0); mm(1, 1, bv1);

  // epilogue: C/D 32x32 map: col=lane&31, row=(r&3)+8*(r>>2)+4*(lane>>5)
  if (!allbf && ks4 == 0) {
#pragma unroll
    for (int mb = 0; mb < 4; ++mb)
#pragma unroll
      for (int nb = 0; nb < 2; ++nb) {
        int nbase = n0 + wr * 128 + mb * 32 + ch5 * 4;
        int b = b0 + wc * 64 + nb * 32 + l31;
#pragma unroll
        for (int r = 0; r < 16; ++r) {
          int n = nbase + (r & 3) + 8 * (r >> 2);
          Out[(size_t)n * NB + b] = acc[mb][nb][r];
        }
      }
  } else {
    int slot = allbf ? ks4 : (ks4 - 1);
    u16* P = Part + (size_t)slot * (NN * NB);
#pragma unroll
    for (int mb = 0; mb < 4; ++mb)
#pragma unroll
      for (int nb = 0; nb < 2; ++nb) {
        int nbase = n0 + wr * 128 + mb * 32 + ch5 * 4;
        int b = b0 + wc * 64 + nb * 32 + l31;
#pragma unroll
        for (int r = 0; r < 16; ++r) {
          int n = nbase + (r & 3) + 8 * (r >> 2);
          P[(size_t)n * NB + b] = f2bf(acc[mb][nb][r]);
        }
      }
  }
}

// ---------------------------------------------------------------------------
// Reduce: allbf ? Out = P0+P1+P2+P3 : Out += P0+P1+P2. 8 floats/thread.
// ---------------------------------------------------------------------------
__global__ __launch_bounds__(256) void k_reduce(float* __restrict__ Out,
                                                const u16* __restrict__ Part,
                                                int allbf) {
  size_t i8 = ((size_t)blockIdx.x * 256 + threadIdx.x) * 8;   // float index
  float a[8];
  int np;
  if (allbf) {
#pragma unroll
    for (int q = 0; q < 8; ++q) a[q] = 0.f;
    np = 4;
  } else {
    float4 x = *(const float4*)(Out + i8);
    float4 y = *(const float4*)(Out + i8 + 4);
    a[0] = x.x; a[1] = x.y; a[2] = x.z; a[3] = x.w;
    a[4] = y.x; a[5] = y.y; a[6] = y.z; a[7] = y.w;
    np = 3;
  }
  for (int p = 0; p < np; ++p) {
    uint4 v = *(const uint4*)(Part + (size_t)p * (NN * NB) + i8);
    a[0] += bf2f((u16)(v.x & 0xFFFFu)); a[1] += bf2f((u16)(v.x >> 16));
    a[2] += bf2f((u16)(v.y & 0xFFFFu)); a[3] += bf2f((u16)(v.y >> 16));
    a[4] += bf2f((u16)(v.z & 0xFFFFu)); a[5] += bf2f((u16)(v.z >> 16));
    a[6] += bf2f((u16)(v.w & 0xFFFFu)); a[7] += bf2f((u16)(v.w >> 16));
  }
  *(float4*)(Out + i8)     = make_float4(a[0], a[1], a[2], a[3]);
  *(float4*)(Out + i8 + 4) = make_float4(a[4], a[5], a[6], a[7]);
}

// ---------------------------------------------------------------------------
extern "C" void kernel_launch(void* const* d_in, const int* in_sizes, int n_in,
                              void* d_out, int out_size, void* d_ws, size_t ws_size,
                              hipStream_t stream) {
  const float* u  = (const float*)d_in[0];   // (1024, 512)
  const float* w  = (const float*)d_in[1];   // (256, 33, 512)
  const float* bs = (const float*)d_in[2];   // (256, 33, 1)
  const float* xi = (const float*)d_in[3];   // (256, 4128)
  float* out = (float*)d_out;                // (4096, 1024) f32

  u16* xiT  = (u16*)d_ws;                          //  2,113,536 B
  u16* Gt   = (u16*)((char*)d_ws + 2113536);       // 17,301,504 B -> 19,415,040
  u16* Wbf  = (u16*)((char*)d_ws + 19415040);      //  8,650,752 B (dead after gemm1)
  u16* Ubf  = (u16*)((char*)d_ws + 28065792);      //  1,048,576 B (dead after gemm1)
  // Part aliases Wbf/Ubf (gemm2 runs after gemm1).
  u16* Part = (u16*)((char*)d_ws + 19415040);
  const int allbf = (ws_size >= 52969472ull) ? 1 : 0;

  k_prep<<<5768, 256, 0, stream>>>(w, u, xi, Wbf, Ubf, xiT);
  k_gemm1<<<dim3(66, 8), 256, 0, stream>>>(Wbf, Ubf, bs, Gt);
  k_gemm2<<<256, 512, 0, stream>>>(xiT, Gt, out, Part, allbf);
  k_reduce<<<2048, 256, 0, stream>>>(out, Part, allbf);
}

// Round 20
// 98.897 us; speedup vs baseline: 1.0893x; 1.0893x over previous
//
#include <hip/hip_runtime.h>
#include <hip/hip_bf16.h>

typedef __attribute__((ext_vector_type(8))) short bf16x8;
typedef __attribute__((ext_vector_type(4))) float f32x4;
typedef unsigned int u32;
typedef unsigned short u16;

#define XI_ROW 4128   // N + 2L
#define KP     8448   // M * W, k' = j*256 + m
#define NB     1024
#define NN     4096
#define DDIM   512

__device__ __forceinline__ u16 f2bf(float f) {
  union { float f; unsigned u; } c; c.f = f;
  return (u16)((c.u + 0x7FFFu + ((c.u >> 16) & 1u)) >> 16);
}
__device__ __forceinline__ float bf2f(u16 h) {
  union { u32 u; float f; } c; c.u = ((u32)h) << 16; return c.f;
}
__device__ __forceinline__ u32 pk2bf(float a, float b) {
  return (u32)f2bf(a) | ((u32)f2bf(b) << 16);
}
__device__ __forceinline__ void gld16(const u16* g, u16* l) {
  __builtin_amdgcn_global_load_lds(
      (const __attribute__((address_space(1))) u32*)(const void*)g,
      (__attribute__((address_space(3))) u32*)(void*)l, 16, 0, 0);
}

#define BAR() __builtin_amdgcn_s_barrier()
#define LGKM0() asm volatile("s_waitcnt lgkmcnt(0)" ::: "memory")
#define LGKM8() asm volatile("s_waitcnt lgkmcnt(8)" ::: "memory")
#define WAITVM(N) asm volatile("s_waitcnt vmcnt(" #N ")" ::: "memory")
#define SCHED0() __builtin_amdgcn_sched_barrier(0)

// ---------------------------------------------------------------------------
// Fused prep: convW [0,4224), convU [4224,4736), transpose xi [4736,5768).
// ---------------------------------------------------------------------------
__global__ __launch_bounds__(256) void k_prep(
    const float* __restrict__ w, const float* __restrict__ u,
    const float* __restrict__ xi, u16* __restrict__ Wbf,
    u16* __restrict__ Ubf, u16* __restrict__ xiT) {
  __shared__ u16 tile[32][33];
  const int bx = blockIdx.x, t = threadIdx.x;
  if (bx < 4224) {                       // weight f32 -> bf16, k'=j*256+m rows
    int kp = bx * 2 + (t >> 7), tl = t & 127;
    int m = kp & 255, j = kp >> 8;
    float4 v = ((const float4*)(w + (size_t)(m * 33 + j) * DDIM))[tl];
    ((uint2*)(Wbf + (size_t)kp * DDIM))[tl] =
        make_uint2(pk2bf(v.x, v.y), pk2bf(v.z, v.w));
  } else if (bx < 4736) {                // u f32 -> bf16
    int b = (bx - 4224) * 2 + (t >> 7), tl = t & 127;
    float4 v = ((const float4*)(u + (size_t)b * DDIM))[tl];
    ((uint2*)(Ubf + (size_t)b * DDIM))[tl] =
        make_uint2(pk2bf(v.x, v.y), pk2bf(v.z, v.w));
  } else {                               // xi (256x4128) -> xiT (4128x256) bf16
    int bx2 = bx - 4736;
    int cblk = bx2 % 129, mblk = bx2 / 129;
    int c0 = cblk * 32, m0 = mblk * 32;
    int tx = t & 31, ty = t >> 5;
#pragma unroll
    for (int i = 0; i < 4; ++i)
      tile[ty + i * 8][tx] = f2bf(xi[(size_t)(m0 + ty + i * 8) * XI_ROW + c0 + tx]);
    __syncthreads();
#pragma unroll
    for (int i = 0; i < 4; ++i)
      xiT[(size_t)(c0 + ty + i * 8) * 256 + m0 + tx] = tile[tx][ty + i * 8];
  }
}

// ---------------------------------------------------------------------------
// 2-phase pipelined core for GEMM1 (proven): 128x128 tile, 4 waves, BK=64.
// ---------------------------------------------------------------------------
template<int KSTEPS, int AS, int BS>
__device__ __forceinline__ void gemm_pipeline(
    const u16* __restrict__ aSrc, const u16* __restrict__ bSrc,
    u16* As0, u16* As1, u16* Bl0, u16* Bl1,
    int wid, int wr, int wc, int rl, int kg, int rl7,
    f32x4 (&acc)[4][4]) {

  auto stage = [&](u16* Ab, u16* Bb, int kk) {
#pragma unroll
    for (int i = 0; i < 4; ++i)
      gld16(aSrc + (size_t)i * 8 * AS + kk, &Ab[(wid * 4 + i) * 512]);
#pragma unroll
    for (int i = 0; i < 4; ++i)
      gld16(bSrc + (size_t)i * 8 * BS + kk, &Bb[(wid * 4 + i) * 512]);
  };
  auto compute = [&](const u16* Ab, const u16* Bb) {
#pragma unroll
    for (int kh = 0; kh < 2; ++kh) {
      bf16x8 af[4], bfv[4];
#pragma unroll
      for (int fm = 0; fm < 4; ++fm)
        af[fm] = *(const bf16x8*)&Ab[(wr * 64 + fm * 16 + rl) * 64 +
                                     (((kh * 4 + kg) ^ rl7) * 8)];
#pragma unroll
      for (int fn = 0; fn < 4; ++fn)
        bfv[fn] = *(const bf16x8*)&Bb[(wc * 64 + fn * 16 + rl) * 64 +
                                      (((kh * 4 + kg) ^ rl7) * 8)];
      __builtin_amdgcn_s_setprio(1);
#pragma unroll
      for (int fm = 0; fm < 4; ++fm)
#pragma unroll
        for (int fn = 0; fn < 4; ++fn)
          acc[fm][fn] = __builtin_amdgcn_mfma_f32_16x16x32_bf16(
              af[fm], bfv[fn], acc[fm][fn], 0, 0, 0);
      __builtin_amdgcn_s_setprio(0);
    }
  };

  stage(As0, Bl0, 0);
  WAITVM(0);
  BAR();
#pragma unroll 1
  for (int ts = 0; ts < KSTEPS - 2; ts += 2) {
    stage(As1, Bl1, (ts + 1) * 64);
    WAITVM(8);
    BAR();
    compute(As0, Bl0);
    BAR();
    stage(As0, Bl0, (ts + 2) * 64);
    WAITVM(8);
    BAR();
    compute(As1, Bl1);
    BAR();
  }
  stage(As1, Bl1, (KSTEPS - 1) * 64);
  WAITVM(8);
  BAR();
  compute(As0, Bl0);
  BAR();
  WAITVM(0);
  BAR();
  compute(As1, Bl1);
}

// ---------------------------------------------------------------------------
// GEMM1: Gt[b][k'] = sigmoid(Wbf[k',:]·Ubf[b,:] + bias[k'])
// Epilogue: LDS transpose (Lt[128][136]) -> coalesced 16B row stores.
// ---------------------------------------------------------------------------
__global__ __launch_bounds__(256) void k_gemm1(
    const u16* __restrict__ Wbf, const u16* __restrict__ Ubf,
    const float* __restrict__ Bsrc, u16* __restrict__ Gt) {
  __shared__ u16 lds1[32768];            // 64 KB: staging, then Lt
  u16* As0 = lds1;
  u16* As1 = lds1 + 8192;
  u16* Bl0 = lds1 + 16384;
  u16* Bl1 = lds1 + 24576;
  const int r0 = blockIdx.x * 128;
  const int b0 = blockIdx.y * 128;
  const int t = threadIdx.x, lane = t & 63, wid = t >> 6;
  const int wr = wid >> 1, wc = wid & 1;
  const int rl = lane & 15, kg = lane >> 4, rl7 = rl & 7;
  const int lr = lane >> 3, lc = (lane & 7) ^ (lr & 7);
  const u16* aSrc = Wbf + (size_t)(r0 + wid * 32 + lr) * DDIM + lc * 8;
  const u16* bSrc = Ubf + (size_t)(b0 + wid * 32 + lr) * DDIM + lc * 8;

  f32x4 acc[4][4] = {};
  gemm_pipeline<8, DDIM, DDIM>(aSrc, bSrc, As0, As1, Bl0, Bl1,
                               wid, wr, wc, rl, kg, rl7, acc);

  __syncthreads();                       // all waves done reading staging LDS
  u16* Lt = lds1;                        // [128][136] bf16
#pragma unroll
  for (int fm = 0; fm < 4; ++fm) {
    int kloc = wr * 64 + fm * 16 + kg * 4;
    int kbase = r0 + kloc;
    float b4[4];
#pragma unroll
    for (int r = 0; r < 4; ++r) {
      int kk = kbase + r;
      b4[r] = Bsrc[(kk & 255) * 33 + (kk >> 8)];
    }
#pragma unroll
    for (int fn = 0; fn < 4; ++fn) {
      int bloc = wc * 64 + fn * 16 + rl;
      u16 o[4];
#pragma unroll
      for (int r = 0; r < 4; ++r) {
        float x = acc[fm][fn][r] + b4[r];
        o[r] = f2bf(1.0f / (1.0f + __expf(-x)));
      }
      *(uint2*)&Lt[bloc * 136 + kloc] =
          make_uint2((u32)o[0] | ((u32)o[1] << 16),
                     (u32)o[2] | ((u32)o[3] << 16));
    }
  }
  __syncthreads();
  const int bl = t >> 4, j = t & 15;
#pragma unroll
  for (int p = 0; p < 8; ++p) {
    int bloc = p * 16 + bl;
    uint4 v = *(const uint4*)&Lt[bloc * 136 + j * 8];
    *(uint4*)(Gt + (size_t)(b0 + bloc) * KP + r0 + j * 8) = v;
  }
}

// ---------------------------------------------------------------------------
// GEMM2: 256x256 tile, 8 waves (2Mx4N, wave-tile 128x64), BK=64, K-split 4.
// SINGLE-barrier 8-phase (banked r12 config, 60.3µs / MfmaUtil 49%).
// Stage map: ph1 stB(T+1,1)->b1; ph2 stA(T+1,0); ph3 stA(T+1,1);
// ph4 stB(T+2,0)->b0 +vm2; ph5 stB(T+2,1); ph6 stA(T+2,0); ph7 stA(T+2,1);
// ph8 stB(T+3,0)->b1 +vm2. Prologue: T0 full + B(T1,h0), vm2.
// TAIL: only the FINAL iteration skips s2/s3 (r10 lesson).
// ---------------------------------------------------------------------------
__global__ __launch_bounds__(512, 2) void k_gemm2(
    const u16* __restrict__ xiT, const u16* __restrict__ Gt,
    float* __restrict__ Out, u16* __restrict__ Part, int allbf) {
  __shared__ u16 lds[65536];
  const int lid = blockIdx.x;
  const int b0 = (lid & 3) * 256;          // 4 b-tiles
  const int ks = (lid >> 2) & 3;           // 4 K-splits
  const int n0 = (lid >> 4) * 256;         // 16 n-tiles
  const int kOff = (ks < 2) ? ks * 2176 : 4352 + (ks - 2) * 2048;
  const int nt = (ks < 2) ? 34 : 32;       // K-steps (even)

  const int t = threadIdx.x, lane = t & 63, wid = t >> 6;
  const int wr = wid >> 2, wc = wid & 3;   // 2(M) x 4(N) waves
  const int rl = lane & 15, kg = lane >> 4, rl7 = rl & 7;
  const int sr = lane >> 3;                // stage: row within 8-row group
  const int sc = (lane & 7) ^ sr;          // stage: swizzled col-chunk

  const u16* aS = xiT + (size_t)(n0 + wid * 16 + sr) * 256 + kOff + sc * 8;
  const u16* bS = Gt  + (size_t)(b0 + wid * 16 + sr) * KP  + kOff + sc * 8;

  f32x4 acc[8][4] = {};
  bf16x8 af[8], b01[4], b23[4];

  auto stA = [&](int tile, int half, int buf) {
    u16* d = lds + (buf * 4 + half) * 8192 + wid * 1024;
    const u16* s = aS + (size_t)half * 32768 + (size_t)tile * 64;
    gld16(s, d);
    gld16(s + 2048, d + 512);
  };
  auto stB = [&](int tile, int half, int buf) {
    u16* d = lds + (buf * 4 + 2 + half) * 8192 + wid * 1024;
    const u16* s = bS + (size_t)half * 128 * KP + (size_t)tile * 64;
    gld16(s, d);
    gld16(s + (size_t)8 * KP, d + 512);
  };
  auto rdA = [&](int buf, int sub) {
    const u16* p = lds + (buf * 4 + wr) * 8192;
#pragma unroll
    for (int q = 0; q < 4; ++q)
#pragma unroll
      for (int kh = 0; kh < 2; ++kh)
        af[q * 2 + kh] = *(const bf16x8*)
            &p[((sub * 4 + q) * 16 + rl) * 64 + (((kh * 4 + kg) ^ rl7) * 8)];
  };
  auto rdB = [&](int buf, int sub, bf16x8 (&bq)[4]) {
    const u16* p = lds + (buf * 4 + 2 + (wc >> 1)) * 8192;
#pragma unroll
    for (int q = 0; q < 2; ++q)
#pragma unroll
      for (int kh = 0; kh < 2; ++kh)
        bq[q * 2 + kh] = *(const bf16x8*)
            &p[((wc & 1) * 64 + (sub * 2 + q) * 16 + rl) * 64 +
               (((kh * 4 + kg) ^ rl7) * 8)];
  };
  auto mm = [&](int sm, int sn, bf16x8 (&bq)[4]) {
    __builtin_amdgcn_s_setprio(1);
#pragma unroll
    for (int q = 0; q < 4; ++q)
#pragma unroll
      for (int p = 0; p < 2; ++p)
#pragma unroll
        for (int kh = 0; kh < 2; ++kh)
          acc[sm * 4 + q][sn * 2 + p] = __builtin_amdgcn_mfma_f32_16x16x32_bf16(
              af[q * 2 + kh], bq[p * 2 + kh], acc[sm * 4 + q][sn * 2 + p], 0, 0, 0);
    __builtin_amdgcn_s_setprio(0);
  };

  // s2: T+2 valid (stages ph4-7); s3: T+3 valid (stage ph8)
  auto runIter = [&](int T, bool s2, bool s3) {
    // ph1: quad(0,0) tile T (buf0) — 12 ds_reads
    rdA(0, 0); rdB(0, 0, b01); stB(T + 1, 1, 1);
    LGKM8(); SCHED0(); BAR(); LGKM0(); SCHED0(); mm(0, 0, b01);
    // ph2: quad(0,1)
    rdB(0, 1, b23); stA(T + 1, 0, 1);
    SCHED0(); BAR(); LGKM0(); SCHED0(); mm(0, 1, b23);
    // ph3: quad(1,0)
    rdA(0, 1); stA(T + 1, 1, 1);
    SCHED0(); BAR(); LGKM0(); SCHED0(); mm(1, 0, b01);
    // ph4: quad(1,1) [no ds_reads] — buf1 must be landed for ph5 reads
    if (s2) { stB(T + 2, 0, 0); WAITVM(2); } else { WAITVM(0); }
    SCHED0(); BAR(); SCHED0(); mm(1, 1, b23);
    // ph5: quad(0,0) tile T+1 (buf1) — 12 ds_reads
    rdA(1, 0); rdB(1, 0, b01); if (s2) stB(T + 2, 1, 0);
    LGKM8(); SCHED0(); BAR(); LGKM0(); SCHED0(); mm(0, 0, b01);
    // ph6: quad(0,1)
    rdB(1, 1, b23); if (s2) stA(T + 2, 0, 0);
    SCHED0(); BAR(); LGKM0(); SCHED0(); mm(0, 1, b23);
    // ph7: quad(1,0)
    rdA(1, 1); if (s2) stA(T + 2, 1, 0);
    SCHED0(); BAR(); LGKM0(); SCHED0(); mm(1, 0, b01);
    // ph8: quad(1,1) — buf0 must be landed for next-iter ph1 reads
    if (s3) { stB(T + 3, 0, 1); WAITVM(2); }
    else if (s2) { WAITVM(0); }
    SCHED0(); BAR(); SCHED0(); mm(1, 1, b23);
  };

  // prologue: T0 complete (buf0, 8 loads) + T1's B-h0 (2 loads).
  stA(0, 0, 0); stA(0, 1, 0); stB(0, 0, 0); stB(0, 1, 0);
  stB(1, 0, 1);
  WAITVM(2);
  BAR();

  const int nIter = nt >> 1;           // 17 or 16
#pragma unroll 1
  for (int it = 0; it < nIter - 1; ++it) runIter(it * 2, true, true);
  runIter((nIter - 1) * 2, false, false);   // only the FINAL iter skips s2/s3

  // epilogue
  if (!allbf && ks == 0) {
#pragma unroll
    for (int fm = 0; fm < 8; ++fm)
#pragma unroll
      for (int fn = 0; fn < 4; ++fn) {
        int n = n0 + wr * 128 + fm * 16 + kg * 4;
        int b = b0 + wc * 64 + fn * 16 + rl;
#pragma unroll
        for (int r = 0; r < 4; ++r)
          Out[(size_t)(n + r) * NB + b] = acc[fm][fn][r];
      }
  } else {
    int slot = allbf ? ks : (ks - 1);
    u16* P = Part + (size_t)slot * (NN * NB);
#pragma unroll
    for (int fm = 0; fm < 8; ++fm)
#pragma unroll
      for (int fn = 0; fn < 4; ++fn) {
        int n = n0 + wr * 128 + fm * 16 + kg * 4;
        int b = b0 + wc * 64 + fn * 16 + rl;
#pragma unroll
        for (int r = 0; r < 4; ++r)
          P[(size_t)(n + r) * NB + b] = f2bf(acc[fm][fn][r]);
      }
  }
}

// ---------------------------------------------------------------------------
// Reduce: allbf ? Out = P0+P1+P2+P3 : Out += P0+P1+P2
// ---------------------------------------------------------------------------
__global__ __launch_bounds__(256) void k_reduce(float* __restrict__ Out,
                                                const u16* __restrict__ Part,
                                                int allbf) {
  size_t i = (size_t)blockIdx.x * 256 + threadIdx.x;   // float4 index
  float4 a;
  int np;
  if (allbf) { a = make_float4(0.f, 0.f, 0.f, 0.f); np = 4; }
  else       { a = ((const float4*)Out)[i];          np = 3; }
  for (int p = 0; p < np; ++p) {
    ushort4 v = ((const ushort4*)(Part + (size_t)p * (NN * NB)))[i];
    a.x += bf2f(v.x); a.y += bf2f(v.y); a.z += bf2f(v.z); a.w += bf2f(v.w);
  }
  ((float4*)Out)[i] = a;
}

// ---------------------------------------------------------------------------
extern "C" void kernel_launch(void* const* d_in, const int* in_sizes, int n_in,
                              void* d_out, int out_size, void* d_ws, size_t ws_size,
                              hipStream_t stream) {
  const float* u  = (const float*)d_in[0];   // (1024, 512)
  const float* w  = (const float*)d_in[1];   // (256, 33, 512)
  const float* bs = (const float*)d_in[2];   // (256, 33, 1)
  const float* xi = (const float*)d_in[3];   // (256, 4128)
  float* out = (float*)d_out;                // (4096, 1024) f32

  u16* xiT  = (u16*)d_ws;                          //  2,113,536 B
  u16* Gt   = (u16*)((char*)d_ws + 2113536);       // 17,301,504 B -> 19,415,040
  u16* Wbf  = (u16*)((char*)d_ws + 19415040);      //  8,650,752 B (dead after gemm1)
  u16* Ubf  = (u16*)((char*)d_ws + 28065792);      //  1,048,576 B (dead after gemm1)
  // Part aliases Wbf/Ubf (gemm2 runs after gemm1).
  u16* Part = (u16*)((char*)d_ws + 19415040);
  const int allbf = (ws_size >= 52969472ull) ? 1 : 0;

  k_prep<<<5768, 256, 0, stream>>>(w, u, xi, Wbf, Ubf, xiT);
  k_gemm1<<<dim3(66, 8), 256, 0, stream>>>(Wbf, Ubf, bs, Gt);
  k_gemm2<<<256, 512, 0, stream>>>(xiT, Gt, out, Part, allbf);
  k_reduce<<<4096, 256, 0, stream>>>(out, Part, allbf);
}